// Round 4
// baseline (127.093 us; speedup 1.0000x reference)
//
#include <hip/hip_runtime.h>
#include <stdint.h>

// covpool: y[b] = (1/256) X X^T - mu mu^T   (B=64, dim=512, M=256)
//
// Round-4: structural rewrite. Three rounds proved the LDS-staged cooperative
// GEMM is schedule-bound (~36-45us regardless of barriers/occupancy; all pipes
// <11% busy). Operands are tiny (x as bf16 = 16 MB = 2 MB/XCD with batch-affine
// swizzle -> L2-resident), so staging is unnecessary: L2 at 34.5 TB/s feeds
// 64x64 wave tiles (32 FLOP/B) up to ~1.1 PF >> the 8.6 GFLOP needed.
//
//   kernel 1 (prep): x f32 -> bf16 (RNE, identical numerics to prior rounds)
//                    into workspace, + row sums -> mu. Pure streaming.
//   kernel 2 (gemm): full-square 16 tiles/batch, 1024 blocks = 4/CU all
//                    resident. ZERO LDS, ZERO barriers. Each lane loads its
//                    exact MFMA fragment (row rl, k-chunk q — the same mapping
//                    the old swizzled LDS delivered) straight from L2-resident
//                    bf16. Per-wave line traffic is already minimal (each line
//                    once). Epilogue: 64 nontemporal dword stores from acc.
//
// Op is write-bound: floor = 64 MB y + 32 MB x ~= 15 us.

typedef __attribute__((ext_vector_type(8))) short bf16x8;   // 8 bf16 = 4 VGPRs
typedef __attribute__((ext_vector_type(4))) float f32x4;

static __device__ __forceinline__ unsigned short f2bf(float f) {
    union { float f; uint32_t u; } c; c.f = f;
    uint32_t u = c.u;
    return (unsigned short)((u + 0x7FFFu + ((u >> 16) & 1u)) >> 16);  // RNE
}

// ---------------- kernel 1: convert + row means ----------------
// 1024 blocks x 256 threads. Block = one 32-row segment of one batch.
// Batch->XCD mapping matches kernel 2 (blk&7 = xcd) so converted panels land
// in the L2 that will consume them.
__global__ __launch_bounds__(256) void covpool_prep(const float* __restrict__ x,
                                                    unsigned short* __restrict__ xbf,
                                                    float* __restrict__ mu) {
    const int blk = blockIdx.x;
    const int xcd = blk & 7, r = blk >> 3;       // r: 0..127
    const int b   = xcd * 8 + (r >> 4);          // 0..63
    const int seg = r & 15;                      // 32-row segment
    const size_t rowbase = (size_t)b * 512 + seg * 32;
    const float* xs = x + rowbase * 256;
    unsigned short* xd = xbf + rowbase * 256;
    const int tid = threadIdx.x;

#pragma unroll
    for (int it = 0; it < 4; ++it) {
        const int cid = it * 256 + tid;          // 8-float chunk id, 0..1023
        const int row = cid >> 5;                // 0..31 (32 chunks/row)
        const int sub = cid & 31;
        const float* g = xs + row * 256 + sub * 8;
        // nontemporal reads: x is read-once; keep L2 for the bf16 panels
        f32x4 v0 = __builtin_nontemporal_load((const f32x4*)g);
        f32x4 v1 = __builtin_nontemporal_load((const f32x4*)(g + 4));
        float s = (v0.x + v0.y + v0.z + v0.w) + (v1.x + v1.y + v1.z + v1.w);
        // row sum across the 32 lanes covering this row (xor<32 stays in group)
        s += __shfl_xor(s, 1, 64);  s += __shfl_xor(s, 2, 64);
        s += __shfl_xor(s, 4, 64);  s += __shfl_xor(s, 8, 64);
        s += __shfl_xor(s, 16, 64);
        bf16x8 o;
        o[0] = (short)f2bf(v0.x); o[1] = (short)f2bf(v0.y);
        o[2] = (short)f2bf(v0.z); o[3] = (short)f2bf(v0.w);
        o[4] = (short)f2bf(v1.x); o[5] = (short)f2bf(v1.y);
        o[6] = (short)f2bf(v1.z); o[7] = (short)f2bf(v1.w);
        *(bf16x8*)(xd + row * 256 + sub * 8) = o;   // plain store: want it in L2
        if (sub == 0) mu[rowbase + row] = s * (1.0f / 256.0f);
    }
}

// ---------------- kernel 2: barrier-free MFMA GEMM ----------------
// 1024 blocks x 256 threads: 64 batches x 16 (tm,tn) tiles of 128x128.
// 4 waves/block, each owns a 64x64 sub-tile (acc[4][4]).
__global__ __launch_bounds__(256, 4) void covpool_gemm(const unsigned short* __restrict__ xbf,
                                                       const float* __restrict__ mu,
                                                       float* __restrict__ y) {
    const int blk = blockIdx.x;
    const int xcd = blk & 7, r = blk >> 3;       // r: 0..127
    const int b   = xcd * 8 + (r >> 4);          // 0..63
    const int t   = r & 15;
    const int tm = t >> 2, tn = t & 3;

    const int tid  = threadIdx.x;
    const int lane = tid & 63;
    const int wave = tid >> 6;
    const int wm = (wave >> 1) * 64;
    const int wn = (wave & 1) * 64;
    const int rl = lane & 15;
    const int q  = lane >> 4;

    // Per-lane fragment bases: A row (wm+i*16+rl), k = kk*32 + q*8 (+0..7).
    // Same (row, k-chunk=q) mapping the old swizzled-LDS read produced.
    const unsigned short* Ap = xbf + ((size_t)b * 512 + tm * 128 + wm + rl) * 256 + q * 8;
    const unsigned short* Bp = xbf + ((size_t)b * 512 + tn * 128 + wn + rl) * 256 + q * 8;

    f32x4 acc[4][4] = {};
#pragma unroll
    for (int kk = 0; kk < 8; ++kk) {
        bf16x8 af[4], bfr[4];
#pragma unroll
        for (int i = 0; i < 4; ++i)
            af[i] = *(const bf16x8*)(Ap + (size_t)i * 16 * 256 + kk * 32);
#pragma unroll
        for (int jj = 0; jj < 4; ++jj)
            bfr[jj] = *(const bf16x8*)(Bp + (size_t)jj * 16 * 256 + kk * 32);
#pragma unroll
        for (int i = 0; i < 4; ++i)
#pragma unroll
            for (int jj = 0; jj < 4; ++jj)
                acc[i][jj] = __builtin_amdgcn_mfma_f32_16x16x32_bf16(
                    af[i], bfr[jj], acc[i][jj], 0, 0, 0);
    }

    // Epilogue: y[row][col] = acc/256 - mu_r*mu_c, straight from registers.
    const float* muR = mu + b * 512 + tm * 128 + wm;
    const float* muC = mu + b * 512 + tn * 128 + wn;
    f32x4 ma[4];
#pragma unroll
    for (int i = 0; i < 4; ++i)
        ma[i] = *(const f32x4*)(muR + i * 16 + q * 4);   // rows q*4..q*4+3 of block i

    float* yb = y + (size_t)b * 512 * 512;
    const float inv256 = 1.0f / 256.0f;
#pragma unroll
    for (int jj = 0; jj < 4; ++jj) {
        const float mb = muC[jj * 16 + rl];
#pragma unroll
        for (int i = 0; i < 4; ++i) {
            const size_t rbase = (size_t)(tm * 128 + wm + i * 16 + q * 4) * 512
                               + tn * 128 + wn + jj * 16 + rl;
#pragma unroll
            for (int rr = 0; rr < 4; ++rr)
                __builtin_nontemporal_store(acc[i][jj][rr] * inv256 - ma[i][rr] * mb,
                                            yb + rbase + (size_t)rr * 512);
        }
    }
}

extern "C" void kernel_launch(void* const* d_in, const int* in_sizes, int n_in,
                              void* d_out, int out_size, void* d_ws, size_t ws_size,
                              hipStream_t stream) {
    const float* x = (const float*)d_in[0];
    float* yout = (float*)d_out;
    // workspace layout: [0,16MB) xbf (64*512*256 bf16), [16MB, +128KB) mu f32
    unsigned short* xbf = (unsigned short*)d_ws;
    float* mu = (float*)((char*)d_ws + (size_t)64 * 512 * 256 * 2);
    (void)ws_size; (void)in_sizes; (void)n_in; (void)out_size;
    covpool_prep<<<1024, 256, 0, stream>>>(x, xbf, mu);
    covpool_gemm<<<1024, 256, 0, stream>>>(xbf, mu, yout);
}